// Round 6
// baseline (480.365 us; speedup 1.0000x reference)
//
#include <hip/hip_runtime.h>

// OT_GNN: 2x GCN -> per-node fused-GW distance to 10 templates -> linear head.
// R6: (1) gemm1 -> MFMA 16x16x32 bf16 (W1 staged to LDS in B-frag layout,
// A-frags as contiguous 16B loads, C/D layout col=lane&15,row=quad*4+reg);
// (2) hist_kernel dropped (scatter's pos counter IS the in-degree);
// (3) norms fused into the second gather (butterfly reduce), int4 slot reads.
// Certificate (R4): K = exp(-5(M+tens)) == 0 exactly in fp32 when
// (sqrt(tn2min)-sqrt(xn2max))^2 >= 26, since tens >= -2 => dist == 0 exact.

#define NN   20000
#define EE   320000
#define FIN  512
#define HID  64
#define KNEI 8
#define LSZ  9      // K_NEI + 1
#define NTPL 10
#define NTN  8
#define NCLS 6
#define CAP  48     // bucket capacity per node (max in-degree ~34)

typedef unsigned short bf16_t;
typedef unsigned short us8 __attribute__((ext_vector_type(8)));
typedef short s16x8 __attribute__((ext_vector_type(8)));
typedef float f32x4 __attribute__((ext_vector_type(4)));

__device__ __forceinline__ float b2f(bf16_t u) {
  union { unsigned int i; float f; } v; v.i = ((unsigned int)u) << 16; return v.f;
}
__device__ __forceinline__ bf16_t f2b(float f) {
  union { float f; unsigned int i; } v; v.f = f;
  unsigned int x = v.i;
  return (bf16_t)((x + 0x7fffu + ((x >> 16) & 1u)) >> 16);  // RNE
}
__device__ __forceinline__ float ldf(const void* p, long i, int fp32) {
  return fp32 ? ((const float*)p)[i] : b2f(((const bf16_t*)p)[i]);
}
__device__ __forceinline__ int ldi(const void* p, long i, int i64) {
  return i64 ? (int)((const long long*)p)[i] : ((const int*)p)[i];
}
__device__ __forceinline__ float frcp(float x) { return __builtin_amdgcn_rcpf(x); }

// ---------- dtype probe + template row-norm mins ----------
__global__ __launch_bounds__(128) void probe_kernel(const void* __restrict__ x,
                                                    const void* __restrict__ ei,
                                                    const void* __restrict__ tfeat,
                                                    int* __restrict__ flags,
                                                    float* __restrict__ tn2min) {
  __shared__ int sfl[2];
  __shared__ float tn2s[80];
  int tid = threadIdx.x;
  if (tid == 0) {
    int sane = 0;
    for (int k = 0; k < 64; k += 2) {
      bf16_t u = ((const bf16_t*)x)[k];
      int e = (u >> 7) & 0xff;
      if (e >= 112 && e <= 142) sane++;
    }
    int f0 = (sane < 24) ? 1 : 0;
    int zc = 0;
    for (int k = 1; k < 64; k += 2)
      if (((const int*)ei)[k] == 0) zc++;
    int f1 = (zc >= 16) ? 1 : 0;
    flags[0] = f0; flags[1] = f1;
    sfl[0] = f0; sfl[1] = f1;
  }
  __syncthreads();
  if (tid < 80) {
    int fF = sfl[0];
    float s = 0.f;
    for (int k = 0; k < HID; ++k) {
      float v = ldf(tfeat, (long)tid * HID + k, fF);
      s += v * v;
    }
    tn2s[tid] = s;
  }
  __syncthreads();
  if (tid == 0) {
    float gmin = 1e30f;
    for (int t = 0; t < NTPL; ++t) {
      float m = tn2s[t * 8];
      for (int r = 1; r < 8; ++r) m = fminf(m, tn2s[t * 8 + r]);
      tn2min[t] = m;
      gmin = fminf(gmin, m);
    }
    tn2min[NTPL] = gmin;
  }
}

// ---------- bucket scatter: pos becomes in-degree, slot holds sources -------
__global__ __launch_bounds__(256) void scatter_kernel(const void* __restrict__ ei,
                                                      int* __restrict__ pos,
                                                      int* __restrict__ slot,
                                                      const int* __restrict__ flags) {
  int i = blockIdx.x * 256 + threadIdx.x;
  if (i >= EE) return;
  int i64 = flags[1];
  int s = ldi(ei, i, i64);
  int d = ldi(ei, (long)EE + i, i64);
  int p = atomicAdd(&pos[d], 1);
  if (p < CAP) slot[d * CAP + p] = s;
}
__global__ __launch_bounds__(256) void dinv_kernel(const int* __restrict__ cnt,
                                                   float* __restrict__ dinv) {
  int i = blockIdx.x * 256 + threadIdx.x;
  if (i < NN) dinv[i] = rsqrtf((float)cnt[i] + 1.0f);   // +1 self loop
}

// ---------- GEMM1 via MFMA: xw1 = x @ W1 ----------
// Each wave: 16 rows x 64 cols. W1 staged in LDS pre-swizzled to B-frag layout.
__global__ __launch_bounds__(256, 2) void gemm1_kernel(const void* __restrict__ x,
                                                       const void* __restrict__ W1,
                                                       float* __restrict__ xw1,
                                                       const int* __restrict__ flags) {
  __shared__ s16x8 Wf[16][4][64];   // [kk][nt][lane], 64 KB
  const int tid = threadIdx.x;
  const int fF = flags[0];
  if (!fF) {
    const bf16_t* wp = (const bf16_t*)W1;
    for (int idx = tid; idx < FIN * HID; idx += 256) {
      int k = idx >> 6, n = idx & 63;
      int kk = k >> 5, q = (k >> 3) & 3, j = k & 7;
      int nt = n >> 4, m = n & 15;
      ((bf16_t*)&Wf[kk][nt][q * 16 + m])[j] = wp[idx];
    }
  }
  __syncthreads();
  const int wid = blockIdx.x * 4 + (tid >> 6);
  const int lane = tid & 63;
  if (wid >= NN / 16) return;
  const int row0 = wid * 16;
  if (!fF) {
    // A-frag: A[m][k], m=lane&15, k=quad*8+j  -> one 16B load per k-step
    const bf16_t* xr = (const bf16_t*)x + (long)(row0 + (lane & 15)) * FIN
                       + (lane >> 4) * 8;
    f32x4 acc0 = {0.f, 0.f, 0.f, 0.f}, acc1 = acc0, acc2 = acc0, acc3 = acc0;
#pragma unroll
    for (int kk = 0; kk < 16; ++kk) {
      s16x8 a = *(const s16x8*)(xr + kk * 32);
      acc0 = __builtin_amdgcn_mfma_f32_16x16x32_bf16(a, Wf[kk][0][lane], acc0, 0, 0, 0);
      acc1 = __builtin_amdgcn_mfma_f32_16x16x32_bf16(a, Wf[kk][1][lane], acc1, 0, 0, 0);
      acc2 = __builtin_amdgcn_mfma_f32_16x16x32_bf16(a, Wf[kk][2][lane], acc2, 0, 0, 0);
      acc3 = __builtin_amdgcn_mfma_f32_16x16x32_bf16(a, Wf[kk][3][lane], acc3, 0, 0, 0);
    }
    // C/D: col = lane&15, row = (lane>>4)*4 + reg
    const int rbase = row0 + (lane >> 4) * 4;
    const int c = lane & 15;
#pragma unroll
    for (int r = 0; r < 4; ++r) {
      float* o = xw1 + (long)(rbase + r) * HID + c;
      o[0]  = acc0[r];
      o[16] = acc1[r];
      o[32] = acc2[r];
      o[48] = acc3[r];
    }
  } else {
    // fp32 fallback (unused when inputs are bf16)
    const float* wp = (const float*)W1;
    for (int r = 0; r < 16; ++r) {
      const float* x0 = (const float*)x + (long)(row0 + r) * FIN;
      float a = 0.f;
      for (int k = 0; k < FIN; ++k) a += x0[k] * wp[k * HID + lane];
      xw1[(long)(row0 + r) * HID + lane] = a;
    }
  }
}

// ---------- GEMM2: xw2 = h1 @ W2 (float4 h loads) ----------
__global__ __launch_bounds__(256) void gemm2_kernel(const float* __restrict__ h,
                                                    const void* __restrict__ W2,
                                                    float* __restrict__ xw2,
                                                    const int* __restrict__ flags) {
  int wave = blockIdx.x * 4 + (threadIdx.x >> 6);
  int lane = threadIdx.x & 63;
  int row0 = wave * 4;
  if (row0 >= NN) return;
  int fF = flags[0];
  float a0 = 0.f, a1 = 0.f, a2 = 0.f, a3 = 0.f;
  const float* h0 = h + (long)row0 * HID;
#pragma unroll 4
  for (int k4 = 0; k4 < HID / 4; ++k4) {
    float4 r0 = *(const float4*)(h0 + k4 * 4);
    float4 r1 = *(const float4*)(h0 + HID + k4 * 4);
    float4 r2 = *(const float4*)(h0 + 2 * HID + k4 * 4);
    float4 r3 = *(const float4*)(h0 + 3 * HID + k4 * 4);
#pragma unroll
    for (int q = 0; q < 4; ++q) {
      float w = ldf(W2, (k4 * 4 + q) * HID + lane, fF);
      float e0 = (q == 0) ? r0.x : (q == 1) ? r0.y : (q == 2) ? r0.z : r0.w;
      float e1 = (q == 0) ? r1.x : (q == 1) ? r1.y : (q == 2) ? r1.z : r1.w;
      float e2 = (q == 0) ? r2.x : (q == 1) ? r2.y : (q == 2) ? r2.z : r2.w;
      float e3 = (q == 0) ? r3.x : (q == 1) ? r3.y : (q == 2) ? r3.z : r3.w;
      a0 += e0 * w; a1 += e1 * w; a2 += e2 * w; a3 += e3 * w;
    }
  }
  xw2[(long)(row0 + 0) * HID + lane] = a0;
  xw2[(long)(row0 + 1) * HID + lane] = a1;
  xw2[(long)(row0 + 2) * HID + lane] = a2;
  xw2[(long)(row0 + 3) * HID + lane] = a3;
}

// ---------- GCN aggregation via bucket gather ----------
// mode 1: + bias, relu (layer 1).  mode 0: store raw h2, also write
// n2[n] = ||h2[n] + bias||^2 (fused norms for the fgw certificate).
__global__ __launch_bounds__(256) void gather_kernel(const float* __restrict__ xw,
                                                     const float* __restrict__ dinv,
                                                     const int* __restrict__ cnt,
                                                     const int* __restrict__ slot,
                                                     float* __restrict__ h,
                                                     float* __restrict__ n2,
                                                     const void* __restrict__ bias,
                                                     const int* __restrict__ flags,
                                                     int mode) {
  int n = blockIdx.x * 4 + (threadIdx.x >> 6);
  if (n >= NN) return;
  int c = threadIdx.x & 63;
  float dn = dinv[n];
  float acc = xw[(long)n * HID + c] * dn;      // self term
  int m = cnt[n]; if (m > CAP) m = CAP;
  const int* sl = slot + (long)n * CAP;
  for (int e0 = 0; e0 < m; e0 += 4) {
    int4 s4 = *(const int4*)(sl + e0);
    if (e0 + 0 < m) acc += xw[(long)s4.x * HID + c] * dinv[s4.x];
    if (e0 + 1 < m) acc += xw[(long)s4.y * HID + c] * dinv[s4.y];
    if (e0 + 2 < m) acc += xw[(long)s4.z * HID + c] * dinv[s4.z];
    if (e0 + 3 < m) acc += xw[(long)s4.w * HID + c] * dinv[s4.w];
  }
  acc *= dn;
  float b = ldf(bias, c, flags[0]);
  if (mode) {
    acc += b;
    acc = acc > 0.f ? acc : 0.f;
    h[(long)n * HID + c] = acc;
  } else {
    h[(long)n * HID + c] = acc;
    float v = acc + b;
    float s = v * v;
    s += __shfl_xor(s, 1); s += __shfl_xor(s, 2); s += __shfl_xor(s, 4);
    s += __shfl_xor(s, 8); s += __shfl_xor(s, 16); s += __shfl_xor(s, 32);
    if (c == 0) n2[n] = s;
  }
}

// ---------- FGW: 4 nodes/block, 8-lane octet per (node, template) ----------
#define NODES_PB 4
#define TPN 80            // threads per node (10 templates x 8 lanes)
#define XLP 65            // padded xl row stride

__global__ __launch_bounds__(320, 2) void fgw_kernel(
    const float* __restrict__ h2,        // [NN,64] fp32 ws (pre-b2)
    const void* __restrict__ b2v,
    const void* __restrict__ nbr_idx,
    const void* __restrict__ nbr_mask,
    const void* __restrict__ C_local,
    const void* __restrict__ tmpl,       // [10,8,8]
    const void* __restrict__ tfeat,      // [10,8,64]
    const void* __restrict__ Wlin,       // [74,6]
    const void* __restrict__ blin,       // [6]
    void* __restrict__ out,              // [NN,6]
    const int* __restrict__ flags,
    const float* __restrict__ tn2min,    // [11]: per-t mins + global min
    const float* __restrict__ n2)        // [NN] node norm^2
{
  const int tid = threadIdx.x;
  const int fF = flags[0];
  const int fI = flags[1];
  const int nb = tid / TPN;
  const int local = tid - nb * TPN;      // [0,80)
  const int t = local >> 3;
  const int j = local & 7;
  const int n = blockIdx.x * NODES_PB + nb;
  const int lane = tid & 63;
  const int ob = lane & 56;

  __shared__ float xlS[NODES_PB][LSZ][XLP];
  __shared__ float C1S[NODES_PB][81];
  __shared__ float hwS[NODES_PB][LSZ];
  __shared__ float f1S[NODES_PB][LSZ];
  __shared__ float xnS[NODES_PB][LSZ];
  __shared__ float distS[NODES_PB][NTPL];
  __shared__ float xmaxS[NODES_PB];
  __shared__ int   needS[NODES_PB];
  __shared__ int   sidxS[NODES_PB][LSZ];

  if (local < LSZ) {
    int idx = (local == 0) ? n : ldi(nbr_idx, (long)n * KNEI + local - 1, fI);
    sidxS[nb][local] = idx;
    xnS[nb][local] = n2[idx];
  }
  if (local < HID)
    xlS[nb][0][local] = h2[(long)n * HID + local] + ldf(b2v, local, fF);
  __syncthreads();   // B1

  if (local == 0) {
    float xm = xnS[nb][0];
#pragma unroll
    for (int l = 1; l < LSZ; ++l) xm = fmaxf(xm, xnS[nb][l]);
    xmaxS[nb] = xm;
    needS[nb] = ((sqrtf(tn2min[NTPL]) - sqrtf(xm)) >= 5.0990195f) ? 0 : 1;
  }
  __syncthreads();   // B2

  const int need = needS[nb];
  if (need) {
    for (int i = local; i < 8 * HID; i += TPN) {
      int l = 1 + (i >> 6), k = i & 63;
      xlS[nb][l][k] = h2[(long)sidxS[nb][l] * HID + k] + ldf(b2v, k, fF);
    }
    for (int i = local; i < 81; i += TPN)
      C1S[nb][i] = ldf(C_local, (long)n * 81 + i, fF);
  }
  __syncthreads();   // B3

  if (need && local < LSZ) {
    int l = local;
    float msum = 0.f, f1 = 0.f;
#pragma unroll
    for (int jj = 0; jj < LSZ; ++jj) {
      float mj = ldf(nbr_mask, (long)n * LSZ + jj, fF);
      msum += mj;
      float c = C1S[nb][l * LSZ + jj];
      f1 += c * c * mj;
    }
    float inv = frcp(msum);
    hwS[nb][l] = ldf(nbr_mask, (long)n * LSZ + l, fF) * inv;
    f1S[nb][l] = f1 * inv;
  }
  __syncthreads();   // B4

  bool slow = need && ((sqrtf(tn2min[t]) - sqrtf(xmaxS[nb])) < 5.0990195f);
  if (slow) {
    float C2c[NTN];
    float f2h2;
    {
      float s = 0.f;
#pragma unroll
      for (int m = 0; m < NTN; ++m) {
        C2c[m] = ldf(tmpl, t * 64 + m * 8 + j, fF);
        float r = ldf(tmpl, t * 64 + j * 8 + m, fF);
        s += r * r;
      }
      f2h2 = s * 0.125f;
    }
    float hwr[LSZ], f1r[LSZ];
#pragma unroll
    for (int l = 0; l < LSZ; ++l) { hwr[l] = hwS[nb][l]; f1r[l] = f1S[nb][l]; }

    float Mc[LSZ];
    {
      float accI[LSZ];
#pragma unroll
      for (int l = 0; l < LSZ; ++l) accI[l] = 0.f;
      float tn2 = 0.f;
      const long tb = (long)local * HID;
      for (int kb = 0; kb < 8; ++kb) {
        float r[8];
#pragma unroll
        for (int q = 0; q < 8; ++q) r[q] = ldf(tfeat, tb + kb * 8 + q, fF);
#pragma unroll
        for (int q = 0; q < 8; ++q) tn2 += r[q] * r[q];
#pragma unroll
        for (int l = 0; l < LSZ; ++l) {
          float s = 0.f;
#pragma unroll
          for (int q = 0; q < 8; ++q) s += xlS[nb][l][kb * 8 + q] * r[q];
          accI[l] += s;
        }
      }
#pragma unroll
      for (int l = 0; l < LSZ; ++l)
        Mc[l] = xnS[nb][l] + tn2 - 2.f * accI[l];
    }

    float Tc[LSZ], Kc[LSZ], u[LSZ];
#pragma unroll
    for (int l = 0; l < LSZ; ++l) Tc[l] = hwr[l] * 0.125f;

    float v = 1.0f;
    for (int outer = 0; outer < 3; ++outer) {
      float Ac[LSZ];
#pragma unroll
      for (int l = 0; l < LSZ; ++l) {
        float s = 0.f;
#pragma unroll
        for (int l2 = 0; l2 < LSZ; ++l2) s += C1S[nb][l * LSZ + l2] * Tc[l2];
        Ac[l] = s;
      }
#pragma unroll
      for (int l = 0; l < LSZ; ++l) {
        float s = 0.f;
#pragma unroll
        for (int m = 0; m < NTN; ++m) s += __shfl(Ac[l], ob + m) * C2c[m];
        float tens = f1r[l] + f2h2 - 2.f * s;
        Kc[l] = __expf(-5.0f * (Mc[l] + tens));
      }
      v = 1.0f;
      for (int it = 0; it < 5; ++it) {
#pragma unroll
        for (int l = 0; l < LSZ; ++l) {
          float p = Kc[l] * v;
          p += __shfl_xor(p, 1); p += __shfl_xor(p, 2); p += __shfl_xor(p, 4);
          u[l] = hwr[l] * frcp(p + 1e-16f);
        }
        float s = 0.f;
#pragma unroll
        for (int l = 0; l < LSZ; ++l) s += Kc[l] * u[l];
        v = 0.125f * frcp(s + 1e-16f);
      }
#pragma unroll
      for (int l = 0; l < LSZ; ++l) Tc[l] = u[l] * Kc[l] * v;
    }
    {
      float Ac[LSZ];
#pragma unroll
      for (int l = 0; l < LSZ; ++l) {
        float s = 0.f;
#pragma unroll
        for (int l2 = 0; l2 < LSZ; ++l2) s += C1S[nb][l * LSZ + l2] * Tc[l2];
        Ac[l] = s;
      }
      float cl = 0.f;
#pragma unroll
      for (int l = 0; l < LSZ; ++l) {
        float s = 0.f;
#pragma unroll
        for (int m = 0; m < NTN; ++m) s += __shfl(Ac[l], ob + m) * C2c[m];
        float tens = f1r[l] + f2h2 - 2.f * s;
        cl += Tc[l] * 0.5f * (Mc[l] + tens);
      }
      cl += __shfl_xor(cl, 1); cl += __shfl_xor(cl, 2); cl += __shfl_xor(cl, 4);
      if (j == 0) distS[nb][t] = cl;
    }
  } else if (j == 0) {
    distS[nb][t] = 0.f;
  }
  __syncthreads();   // B5

  if (local < NCLS) {
    int c = local;
    float acc = ldf(blin, c, fF);
#pragma unroll
    for (int k = 0; k < HID; ++k)
      acc += xlS[nb][0][k] * ldf(Wlin, k * NCLS + c, fF);
#pragma unroll
    for (int tt = 0; tt < NTPL; ++tt)
      acc += distS[nb][tt] * ldf(Wlin, (HID + tt) * NCLS + c, fF);
    float r = acc > 0.f ? acc : 0.f;
    if (fF) ((float*)out)[(long)n * NCLS + c] = r;
    else    ((bf16_t*)out)[(long)n * NCLS + c] = f2b(r);
  }
}

extern "C" void kernel_launch(void* const* d_in, const int* in_sizes, int n_in,
                              void* d_out, int out_size, void* d_ws, size_t ws_size,
                              hipStream_t stream) {
  (void)in_sizes; (void)n_in; (void)out_size; (void)ws_size;
  const void* x     = d_in[0];
  const void* ei    = d_in[1];
  const void* nbr   = d_in[2];
  const void* nmask = d_in[3];
  const void* Cl    = d_in[4];
  const void* W1    = d_in[5];
  const void* b1    = d_in[6];
  const void* W2    = d_in[7];
  const void* b2    = d_in[8];
  const void* tmpl  = d_in[9];
  const void* tfeat = d_in[10];
  const void* Wlin  = d_in[11];
  const void* blin  = d_in[12];

  // ws layout (4B words): flags[4] | tn2min[12] | dinv NN | n2 NN |
  //                       pos NN | slot CAP*NN | bufA 64NN | bufB 64NN
  int*   flags  = (int*)d_ws;
  float* tn2min = (float*)d_ws + 4;
  float* dinv   = (float*)d_ws + 16;
  float* n2     = dinv + NN;
  int*   pos    = (int*)(n2 + NN);
  int*   slot   = pos + NN;
  float* bufA   = (float*)(slot + (long)CAP * NN);
  float* bufB   = bufA + (long)NN * HID;

  probe_kernel<<<1, 128, 0, stream>>>(x, ei, tfeat, flags, tn2min);

  hipMemsetAsync(pos, 0, NN * sizeof(int), stream);
  scatter_kernel<<<(EE + 255) / 256, 256, 0, stream>>>(ei, pos, slot, flags);
  dinv_kernel<<<(NN + 255) / 256, 256, 0, stream>>>(pos, dinv);

  // layer 1
  gemm1_kernel<<<(NN / 16 + 3) / 4, 256, 0, stream>>>(x, W1, bufA, flags);
  gather_kernel<<<NN / 4, 256, 0, stream>>>(bufA, dinv, pos, slot, bufB,
                                            n2, b1, flags, 1);
  // layer 2 (n2 fused into this gather)
  gemm2_kernel<<<NN / 16, 256, 0, stream>>>(bufB, W2, bufA, flags);
  gather_kernel<<<NN / 4, 256, 0, stream>>>(bufA, dinv, pos, slot, bufB,
                                            n2, b2, flags, 0);

  fgw_kernel<<<NN / NODES_PB, 320, 0, stream>>>(bufB, b2, nbr, nmask, Cl, tmpl,
                                                tfeat, Wlin, blin, d_out, flags,
                                                tn2min, n2);
}